// Round 1
// baseline (3513.634 us; speedup 1.0000x reference)
//
#include <hip/hip_runtime.h>

#define NROWS 16384
#define DIMIN 768
#define CD    256
#define KC    4096

#define BM 128
#define BN 128
#define BK 32

// ---------------- helpers ----------------
__device__ __forceinline__ float wave_sum(float v) {
#pragma unroll
    for (int off = 32; off > 0; off >>= 1) v += __shfl_xor(v, off, 64);
    return v;
}

// ---------------- e2[cb][r] = sum_c E_cb[r][c]^2 : one wave per row ----------------
__global__ void e2_kernel(const float* __restrict__ E1, const float* __restrict__ E2,
                          const float* __restrict__ E3, const float* __restrict__ E4,
                          float* __restrict__ e2) {
    int gw   = (blockIdx.x * blockDim.x + threadIdx.x) >> 6;  // 0..4*KC-1
    int lane = threadIdx.x & 63;
    if (gw >= 4 * KC) return;
    int cb = gw >> 12;
    int r  = gw & (KC - 1);
    const float* E = (cb == 0) ? E1 : (cb == 1) ? E2 : (cb == 2) ? E3 : E4;
    float4 v = *(const float4*)(E + (size_t)r * CD + lane * 4);
    float s  = v.x * v.x + v.y * v.y + v.z * v.z + v.w * v.w;
    s = wave_sum(s);
    if (lane == 0) e2[gw] = s;
}

// ---------------- z2[r] = sum_c ze[r][c]^2 : one wave per row ----------------
__global__ void z2_kernel(const float* __restrict__ ze, float* __restrict__ z2) {
    int gw   = (blockIdx.x * blockDim.x + threadIdx.x) >> 6;
    int lane = threadIdx.x & 63;
    float4 v = *(const float4*)(ze + (size_t)gw * CD + lane * 4);
    float s  = v.x * v.x + v.y * v.y + v.z * v.z + v.w * v.w;
    s = wave_sum(s);
    if (lane == 0) z2[gw] = s;
}

// ---------------- fp32 GEMM: C = A @ B + bias ----------------
// A: MxK row-major (K-contiguous), B: KxN row-major (N-contiguous).
__global__ __launch_bounds__(256, 4)
void enc_gemm(const float* __restrict__ A, const float* __restrict__ B,
              const float* __restrict__ bias, float* __restrict__ C,
              int M, int Kt, int Nt) {
    __shared__ float As[BK][BM + 4];  // transposed: As[k][m]
    __shared__ float Bs[BK][BN + 4];  // natural:    Bs[k][n]
    int nblkN = Nt / BN;
    int mb = blockIdx.x / nblkN, nb = blockIdx.x % nblkN;
    int mBase = mb * BM, nBase = nb * BN;
    int t = threadIdx.x;
    int mg = t >> 4, ng = t & 15;

    float acc[8][8];
#pragma unroll
    for (int i = 0; i < 8; ++i)
#pragma unroll
        for (int j = 0; j < 8; ++j) acc[i][j] = 0.f;

    for (int kB = 0; kB < Kt; kB += BK) {
#pragma unroll
        for (int i = 0; i < 4; ++i) {  // stage A (transpose)
            int idx = i * 256 + t;
            int row = idx >> 3, k4 = idx & 7;
            float4 g = *(const float4*)(A + (size_t)(mBase + row) * Kt + kB + k4 * 4);
            As[k4 * 4 + 0][row] = g.x;
            As[k4 * 4 + 1][row] = g.y;
            As[k4 * 4 + 2][row] = g.z;
            As[k4 * 4 + 3][row] = g.w;
        }
#pragma unroll
        for (int i = 0; i < 4; ++i) {  // stage B (natural)
            int idx = i * 256 + t;
            int row = idx >> 5, c4 = idx & 31;
            float4 g = *(const float4*)(B + (size_t)(kB + row) * Nt + nBase + c4 * 4);
            *(float4*)&Bs[row][c4 * 4] = g;
        }
        __syncthreads();
#pragma unroll 8
        for (int kk = 0; kk < BK; ++kk) {
            float4 a0 = *(const float4*)&As[kk][mg * 8];
            float4 a1 = *(const float4*)&As[kk][mg * 8 + 4];
            float4 b0 = *(const float4*)&Bs[kk][ng * 8];
            float4 b1 = *(const float4*)&Bs[kk][ng * 8 + 4];
            float av[8] = {a0.x, a0.y, a0.z, a0.w, a1.x, a1.y, a1.z, a1.w};
            float bv[8] = {b0.x, b0.y, b0.z, b0.w, b1.x, b1.y, b1.z, b1.w};
#pragma unroll
            for (int im = 0; im < 8; ++im)
#pragma unroll
                for (int in = 0; in < 8; ++in)
                    acc[im][in] = fmaf(av[im], bv[in], acc[im][in]);
        }
        __syncthreads();
    }
    float bv[8];
#pragma unroll
    for (int in = 0; in < 8; ++in) bv[in] = bias[nBase + ng * 8 + in];
#pragma unroll
    for (int im = 0; im < 8; ++im) {
        float4 o0 = make_float4(acc[im][0] + bv[0], acc[im][1] + bv[1],
                                acc[im][2] + bv[2], acc[im][3] + bv[3]);
        float4 o1 = make_float4(acc[im][4] + bv[4], acc[im][5] + bv[5],
                                acc[im][6] + bv[6], acc[im][7] + bv[7]);
        float* cp = C + (size_t)(mBase + mg * 8 + im) * Nt + nBase + ng * 8;
        *(float4*)cp       = o0;
        *(float4*)(cp + 4) = o1;
    }
}

// ---------------- decoder GEMM with on-the-fly decoder_input composition ----------------
// decoder_input = ze1 + ((((zq1+zq2)+zq3)+zq4) - ze1), mirroring np op order.
__global__ __launch_bounds__(256, 4)
void dec_gemm(const float* __restrict__ ze1, const float* __restrict__ q1,
              const float* __restrict__ q2, const float* __restrict__ q3,
              const float* __restrict__ q4, const float* __restrict__ B,
              const float* __restrict__ bias, float* __restrict__ C) {
    __shared__ float As[BK][BM + 4];
    __shared__ float Bs[BK][BN + 4];
    const int Nt = DIMIN, Kt = CD;
    int nblkN = Nt / BN;
    int mb = blockIdx.x / nblkN, nb = blockIdx.x % nblkN;
    int mBase = mb * BM, nBase = nb * BN;
    int t = threadIdx.x;
    int mg = t >> 4, ng = t & 15;

    float acc[8][8];
#pragma unroll
    for (int i = 0; i < 8; ++i)
#pragma unroll
        for (int j = 0; j < 8; ++j) acc[i][j] = 0.f;

    for (int kB = 0; kB < Kt; kB += BK) {
#pragma unroll
        for (int i = 0; i < 4; ++i) {
            int idx = i * 256 + t;
            int row = idx >> 3, k4 = idx & 7;
            size_t off = (size_t)(mBase + row) * CD + kB + k4 * 4;
            float4 z = *(const float4*)(ze1 + off);
            float4 a = *(const float4*)(q1 + off);
            float4 b = *(const float4*)(q2 + off);
            float4 c = *(const float4*)(q3 + off);
            float4 d = *(const float4*)(q4 + off);
            float sx = ((a.x + b.x) + c.x) + d.x;
            float sy = ((a.y + b.y) + c.y) + d.y;
            float sz = ((a.z + b.z) + c.z) + d.z;
            float sw = ((a.w + b.w) + c.w) + d.w;
            As[k4 * 4 + 0][row] = z.x + (sx - z.x);
            As[k4 * 4 + 1][row] = z.y + (sy - z.y);
            As[k4 * 4 + 2][row] = z.z + (sz - z.z);
            As[k4 * 4 + 3][row] = z.w + (sw - z.w);
        }
#pragma unroll
        for (int i = 0; i < 4; ++i) {
            int idx = i * 256 + t;
            int row = idx >> 5, c4 = idx & 31;
            float4 g = *(const float4*)(B + (size_t)(kB + row) * Nt + nBase + c4 * 4);
            *(float4*)&Bs[row][c4 * 4] = g;
        }
        __syncthreads();
#pragma unroll 8
        for (int kk = 0; kk < BK; ++kk) {
            float4 a0 = *(const float4*)&As[kk][mg * 8];
            float4 a1 = *(const float4*)&As[kk][mg * 8 + 4];
            float4 b0 = *(const float4*)&Bs[kk][ng * 8];
            float4 b1 = *(const float4*)&Bs[kk][ng * 8 + 4];
            float av[8] = {a0.x, a0.y, a0.z, a0.w, a1.x, a1.y, a1.z, a1.w};
            float bv[8] = {b0.x, b0.y, b0.z, b0.w, b1.x, b1.y, b1.z, b1.w};
#pragma unroll
            for (int im = 0; im < 8; ++im)
#pragma unroll
                for (int in = 0; in < 8; ++in)
                    acc[im][in] = fmaf(av[im], bv[in], acc[im][in]);
        }
        __syncthreads();
    }
    float bv[8];
#pragma unroll
    for (int in = 0; in < 8; ++in) bv[in] = bias[nBase + ng * 8 + in];
#pragma unroll
    for (int im = 0; im < 8; ++im) {
        float4 o0 = make_float4(acc[im][0] + bv[0], acc[im][1] + bv[1],
                                acc[im][2] + bv[2], acc[im][3] + bv[3]);
        float4 o1 = make_float4(acc[im][4] + bv[4], acc[im][5] + bv[5],
                                acc[im][6] + bv[6], acc[im][7] + bv[7]);
        float* cp = C + (size_t)(mBase + mg * 8 + im) * Nt + nBase + ng * 8;
        *(float4*)cp       = o0;
        *(float4*)(cp + 4) = o1;
    }
}

// ---------------- VQ scores + fused argmin over half the codebook ----------------
// d[m][n] = (z2[m] - 2*(ze[m].E[n])) + e2[n], argmin over n (first-index-wins).
// grid: (NROWS/BM) * 2 blocks; block b: mb = b>>1, half = b&1 (codes half*2048 ..).
__global__ __launch_bounds__(256, 4)
void vq_scores(const float* __restrict__ ze, const float* __restrict__ E,
               const float* __restrict__ e2, const float* __restrict__ z2,
               float* __restrict__ pd, int* __restrict__ pi) {
    __shared__ float As[BK][BM + 4];  // As[k][m] of ze
    __shared__ float Bs[BK][BN + 4];  // Bs[k][n] of E (transposed)
    __shared__ float z2s[BM];
    int mb = blockIdx.x >> 1, half = blockIdx.x & 1;
    int mBase = mb * BM;
    int t = threadIdx.x, mg = t >> 4, ng = t & 15;
    if (t < BM) z2s[t] = z2[mBase + t];

    float bd[8];
    int   bi[8];
#pragma unroll
    for (int i = 0; i < 8; ++i) { bd[i] = 3.4e38f; bi[i] = 0; }

    for (int c = 0; c < 16; ++c) {
        int nBase = half * 2048 + c * 128;
        float acc[8][8];
#pragma unroll
        for (int i = 0; i < 8; ++i)
#pragma unroll
            for (int j = 0; j < 8; ++j) acc[i][j] = 0.f;

        for (int kB = 0; kB < CD; kB += BK) {
#pragma unroll
            for (int i = 0; i < 4; ++i) {  // stage ze tile (transpose)
                int idx = i * 256 + t;
                int row = idx >> 3, k4 = idx & 7;
                float4 g = *(const float4*)(ze + (size_t)(mBase + row) * CD + kB + k4 * 4);
                As[k4 * 4 + 0][row] = g.x;
                As[k4 * 4 + 1][row] = g.y;
                As[k4 * 4 + 2][row] = g.z;
                As[k4 * 4 + 3][row] = g.w;
            }
#pragma unroll
            for (int i = 0; i < 4; ++i) {  // stage E tile (transpose)
                int idx = i * 256 + t;
                int row = idx >> 3, k4 = idx & 7;
                float4 g = *(const float4*)(E + (size_t)(nBase + row) * CD + kB + k4 * 4);
                Bs[k4 * 4 + 0][row] = g.x;
                Bs[k4 * 4 + 1][row] = g.y;
                Bs[k4 * 4 + 2][row] = g.z;
                Bs[k4 * 4 + 3][row] = g.w;
            }
            __syncthreads();
#pragma unroll 8
            for (int kk = 0; kk < BK; ++kk) {
                float4 a0 = *(const float4*)&As[kk][mg * 8];
                float4 a1 = *(const float4*)&As[kk][mg * 8 + 4];
                float4 b0 = *(const float4*)&Bs[kk][ng * 8];
                float4 b1 = *(const float4*)&Bs[kk][ng * 8 + 4];
                float av[8] = {a0.x, a0.y, a0.z, a0.w, a1.x, a1.y, a1.z, a1.w};
                float bv[8] = {b0.x, b0.y, b0.z, b0.w, b1.x, b1.y, b1.z, b1.w};
#pragma unroll
                for (int im = 0; im < 8; ++im)
#pragma unroll
                    for (int in = 0; in < 8; ++in)
                        acc[im][in] = fmaf(av[im], bv[in], acc[im][in]);
            }
            __syncthreads();
        }
        // epilogue: d = (z2 - 2s) + e2, running argmin (ascending n, strict <)
        float e2v[8];
#pragma unroll
        for (int in = 0; in < 8; ++in) e2v[in] = e2[nBase + ng * 8 + in];
#pragma unroll
        for (int im = 0; im < 8; ++im) {
            float z2v = z2s[mg * 8 + im];
#pragma unroll
            for (int in = 0; in < 8; ++in) {
                float dv = fmaf(-2.f, acc[im][in], z2v) + e2v[in];
                if (dv < bd[im]) { bd[im] = dv; bi[im] = nBase + ng * 8 + in; }
            }
        }
    }
    // cross-thread lexicographic (d, idx) reduction per row
    __syncthreads();
    float* rd = &As[0][0];          // 128*16 floats, fits in As
    int*   ri = (int*)&Bs[0][0];
#pragma unroll
    for (int im = 0; im < 8; ++im) {
        int row = mg * 8 + im;
        rd[row * 16 + ng] = bd[im];
        ri[row * 16 + ng] = bi[im];
    }
    __syncthreads();
    if (t < BM) {
        float best = rd[t * 16];
        int besti  = ri[t * 16];
#pragma unroll
        for (int j = 1; j < 16; ++j) {
            float dj = rd[t * 16 + j];
            int ij   = ri[t * 16 + j];
            if (dj < best || (dj == best && ij < besti)) { best = dj; besti = ij; }
        }
        pd[half * NROWS + mBase + t] = best;
        pi[half * NROWS + mBase + t] = besti;
    }
}

// ---------------- combine halves, gather zq, residual, next z2 ----------------
__global__ void vq_finish(const float* __restrict__ ze, const float* __restrict__ E,
                          const float* __restrict__ pd, const int* __restrict__ pi,
                          float* __restrict__ nn_out, float* __restrict__ zq_out,
                          float* __restrict__ ze_next, float* __restrict__ z2_next) {
    int w = threadIdx.x >> 6, lane = threadIdx.x & 63;
    int row = blockIdx.x * 4 + w;
    float d0 = pd[row], d1 = pd[NROWS + row];
    int   i0 = pi[row], i1 = pi[NROWS + row];
    int idx = (d1 < d0) ? i1 : i0;   // tie -> half0 (smaller index) = first-wins
    if (lane == 0) nn_out[row] = (float)idx;
    float4 e = *(const float4*)(E + (size_t)idx * CD + lane * 4);
    float4 z = *(const float4*)(ze + (size_t)row * CD + lane * 4);
    *(float4*)(zq_out + (size_t)row * CD + lane * 4) = e;
    if (ze_next) {
        float4 r = make_float4(z.x - e.x, z.y - e.y, z.z - e.z, z.w - e.w);
        *(float4*)(ze_next + (size_t)row * CD + lane * 4) = r;
        float s = r.x * r.x + r.y * r.y + r.z * r.z + r.w * r.w;
        s = wave_sum(s);
        if (lane == 0) z2_next[row] = s;
    }
}

// ---------------- launch ----------------
extern "C" void kernel_launch(void* const* d_in, const int* in_sizes, int n_in,
                              void* d_out, int out_size, void* d_ws, size_t ws_size,
                              hipStream_t stream) {
    const float* x     = (const float*)d_in[0];
    const float* W_enc = (const float*)d_in[1];
    const float* b_enc = (const float*)d_in[2];
    const float* Ecb[4] = {(const float*)d_in[3], (const float*)d_in[4],
                           (const float*)d_in[5], (const float*)d_in[6]};
    const float* W_dec = (const float*)d_in[7];
    const float* b_dec = (const float*)d_in[8];

    float* out  = (float*)d_out;
    float* xhat = out;                                   // 16384*768
    float* ze[4];
    float* zq[4];
    float* nn[4];
    size_t off = (size_t)NROWS * DIMIN;                  // 12582912
    for (int i = 0; i < 4; ++i) { ze[i] = out + off; off += (size_t)NROWS * CD; }
    for (int i = 0; i < 4; ++i) { zq[i] = out + off; off += (size_t)NROWS * CD; }
    for (int i = 0; i < 4; ++i) { nn[i] = out + off; off += NROWS; }

    float* z2 = (float*)d_ws;                            // 16384
    float* pd = z2 + NROWS;                              // 2*16384
    int*   pi = (int*)(pd + 2 * NROWS);                  // 2*16384
    float* e2 = (float*)(pi + 2 * NROWS);                // 4*4096

    e2_kernel<<<4096, 256, 0, stream>>>(Ecb[0], Ecb[1], Ecb[2], Ecb[3], e2);
    enc_gemm<<<256, 256, 0, stream>>>(x, W_enc, b_enc, ze[0], NROWS, DIMIN, CD);
    z2_kernel<<<4096, 256, 0, stream>>>(ze[0], z2);
    for (int s = 0; s < 4; ++s) {
        vq_scores<<<256, 256, 0, stream>>>(ze[s], Ecb[s], e2 + (size_t)s * KC, z2, pd, pi);
        vq_finish<<<4096, 256, 0, stream>>>(ze[s], Ecb[s], pd, pi, nn[s], zq[s],
                                            (s < 3) ? ze[s + 1] : nullptr, z2);
    }
    dec_gemm<<<768, 256, 0, stream>>>(ze[0], zq[0], zq[1], zq[2], zq[3],
                                      W_dec, b_dec, xhat);
}

// Round 2
// 1733.387 us; speedup vs baseline: 2.0270x; 2.0270x over previous
//
#include <hip/hip_runtime.h>

#define NROWS 16384
#define DIMIN 768
#define CD    256
#define KC    4096

#define BM 128
#define BN 128
#define BK 32
#define MARGIN 0.2f

typedef __attribute__((ext_vector_type(8))) short short8;
typedef __attribute__((ext_vector_type(4))) float f32x4;

#define SWZ(r) ((((r) + ((r) >> 2))) & 3)
#define ASYNC_CP16(gp, lp)                                                     \
    __builtin_amdgcn_global_load_lds(                                          \
        (const __attribute__((address_space(1))) void*)(gp),                   \
        (__attribute__((address_space(3))) void*)(lp), 16, 0, 0)

// ---------------- helpers ----------------
__device__ __forceinline__ float wave_sum(float v) {
#pragma unroll
    for (int off = 32; off > 0; off >>= 1) v += __shfl_xor(v, off, 64);
    return v;
}
__device__ __forceinline__ unsigned short f2bf(float f) {
    unsigned u = __float_as_uint(f);
    unsigned r = (u + 0x7FFFu + ((u >> 16) & 1u)) >> 16;
    return (unsigned short)r;
}
// monotone float<->uint key (handles negatives)
__device__ __forceinline__ unsigned fkey(float f) {
    unsigned u = __float_as_uint(f);
    return (u >> 31) ? ~u : (u | 0x80000000u);
}
__device__ __forceinline__ float funkey(unsigned k) {
    unsigned u = (k >> 31) ? (k ^ 0x80000000u) : ~k;
    return __uint_as_float(u);
}

// ---------------- shared MFMA core: acc[i][j] += Arows_tile . Brows_tile^T ----------------
// Arows/Brows: bf16, row stride 256 (K-contiguous). 128x128 tile, K=256, BK=32.
__device__ __forceinline__ void mfma_core(const unsigned short* __restrict__ Arows,
                                          const unsigned short* __restrict__ Brows,
                                          int mBase, int nBase,
                                          unsigned short* As, unsigned short* Bs,
                                          f32x4 acc[4][4], int t) {
    int w = t >> 6, lane = t & 63;
    int wm = (w >> 1) * 64, wn = (w & 1) * 64;
    int g = lane >> 4, c = lane & 15;

    for (int kB = 0; kB < CD; kB += BK) {
        __syncthreads();
#pragma unroll
        for (int it = 0; it < 2; ++it) {
            int L = w * 128 + it * 64 + lane;  // 16B-chunk index in tile
            int r = L >> 2, p = L & 3;
            int q = p ^ SWZ(r);
            ASYNC_CP16(Arows + (size_t)(mBase + r) * CD + kB + q * 8,
                       &As[(w * 128 + it * 64) * 8]);
            ASYNC_CP16(Brows + (size_t)(nBase + r) * CD + kB + q * 8,
                       &Bs[(w * 128 + it * 64) * 8]);
        }
        __syncthreads();
        short8 a[4], b[4];
#pragma unroll
        for (int i = 0; i < 4; ++i) {
            int ra = wm + i * 16 + c;
            a[i] = *(const short8*)&As[ra * 32 + ((g ^ SWZ(ra)) << 3)];
            int rb = wn + i * 16 + c;
            b[i] = *(const short8*)&Bs[rb * 32 + ((g ^ SWZ(rb)) << 3)];
        }
#pragma unroll
        for (int i = 0; i < 4; ++i)
#pragma unroll
            for (int j = 0; j < 4; ++j)
                acc[i][j] = __builtin_amdgcn_mfma_f32_16x16x32_bf16(a[i], b[j], acc[i][j], 0, 0, 0);
    }
}

// ---------------- E -> bf16 + e2 (fp32) ----------------
__global__ void ecvt_kernel(const float* __restrict__ E1, const float* __restrict__ E2,
                            const float* __restrict__ E3, const float* __restrict__ E4,
                            unsigned short* __restrict__ Ebf, float* __restrict__ e2) {
    int gw   = (blockIdx.x * blockDim.x + threadIdx.x) >> 6;  // 0..16383
    int lane = threadIdx.x & 63;
    int cb = gw >> 12, r = gw & (KC - 1);
    const float* E = (cb == 0) ? E1 : (cb == 1) ? E2 : (cb == 2) ? E3 : E4;
    float4 v = *(const float4*)(E + (size_t)r * CD + lane * 4);
    float s  = v.x * v.x + v.y * v.y + v.z * v.z + v.w * v.w;
    s = wave_sum(s);
    if (lane == 0) e2[gw] = s;
    ushort4 o = make_ushort4(f2bf(v.x), f2bf(v.y), f2bf(v.z), f2bf(v.w));
    *(ushort4*)(Ebf + (size_t)gw * CD + lane * 4) = o;
}

// ---------------- W_dec (256x768) -> WdT (768x256 bf16, transposed) ----------------
__global__ void wcvt_kernel(const float* __restrict__ Wd, unsigned short* __restrict__ WdT) {
    int gid = blockIdx.x * blockDim.x + threadIdx.x;  // 0..196607
    int k = gid / DIMIN, n = gid % DIMIN;
    WdT[(size_t)n * CD + k] = f2bf(Wd[gid]);
}

// ---------------- ze1 -> bf16 + z2 ----------------
__global__ void zecvt_kernel(const float* __restrict__ ze, unsigned short* __restrict__ zebf,
                             float* __restrict__ z2) {
    int gw   = (blockIdx.x * blockDim.x + threadIdx.x) >> 6;
    int lane = threadIdx.x & 63;
    float4 v = *(const float4*)(ze + (size_t)gw * CD + lane * 4);
    float s  = v.x * v.x + v.y * v.y + v.z * v.z + v.w * v.w;
    s = wave_sum(s);
    if (lane == 0) z2[gw] = s;
    ushort4 o = make_ushort4(f2bf(v.x), f2bf(v.y), f2bf(v.z), f2bf(v.w));
    *(ushort4*)(zebf + (size_t)gw * CD + lane * 4) = o;
}

// ---------------- fp32 encoder GEMM (round-1, known good) ----------------
__global__ __launch_bounds__(256, 4)
void enc_gemm(const float* __restrict__ A, const float* __restrict__ B,
              const float* __restrict__ bias, float* __restrict__ C,
              int M, int Kt, int Nt) {
    __shared__ float As[BK][BM + 4];
    __shared__ float Bs[BK][BN + 4];
    int nblkN = Nt / BN;
    int mb = blockIdx.x / nblkN, nb = blockIdx.x % nblkN;
    int mBase = mb * BM, nBase = nb * BN;
    int t = threadIdx.x;
    int mg = t >> 4, ng = t & 15;

    float acc[8][8];
#pragma unroll
    for (int i = 0; i < 8; ++i)
#pragma unroll
        for (int j = 0; j < 8; ++j) acc[i][j] = 0.f;

    for (int kB = 0; kB < Kt; kB += BK) {
#pragma unroll
        for (int i = 0; i < 4; ++i) {
            int idx = i * 256 + t;
            int row = idx >> 3, k4 = idx & 7;
            float4 g = *(const float4*)(A + (size_t)(mBase + row) * Kt + kB + k4 * 4);
            As[k4 * 4 + 0][row] = g.x;
            As[k4 * 4 + 1][row] = g.y;
            As[k4 * 4 + 2][row] = g.z;
            As[k4 * 4 + 3][row] = g.w;
        }
#pragma unroll
        for (int i = 0; i < 4; ++i) {
            int idx = i * 256 + t;
            int row = idx >> 5, c4 = idx & 31;
            float4 g = *(const float4*)(B + (size_t)(kB + row) * Nt + nBase + c4 * 4);
            *(float4*)&Bs[row][c4 * 4] = g;
        }
        __syncthreads();
#pragma unroll 8
        for (int kk = 0; kk < BK; ++kk) {
            float4 a0 = *(const float4*)&As[kk][mg * 8];
            float4 a1 = *(const float4*)&As[kk][mg * 8 + 4];
            float4 b0 = *(const float4*)&Bs[kk][ng * 8];
            float4 b1 = *(const float4*)&Bs[kk][ng * 8 + 4];
            float av[8] = {a0.x, a0.y, a0.z, a0.w, a1.x, a1.y, a1.z, a1.w};
            float bv[8] = {b0.x, b0.y, b0.z, b0.w, b1.x, b1.y, b1.z, b1.w};
#pragma unroll
            for (int im = 0; im < 8; ++im)
#pragma unroll
                for (int in = 0; in < 8; ++in)
                    acc[im][in] = fmaf(av[im], bv[in], acc[im][in]);
        }
        __syncthreads();
    }
    float bv[8];
#pragma unroll
    for (int in = 0; in < 8; ++in) bv[in] = bias[nBase + ng * 8 + in];
#pragma unroll
    for (int im = 0; im < 8; ++im) {
        float4 o0 = make_float4(acc[im][0] + bv[0], acc[im][1] + bv[1],
                                acc[im][2] + bv[2], acc[im][3] + bv[3]);
        float4 o1 = make_float4(acc[im][4] + bv[4], acc[im][5] + bv[5],
                                acc[im][6] + bv[6], acc[im][7] + bv[7]);
        float* cp = C + (size_t)(mBase + mg * 8 + im) * Nt + nBase + ng * 8;
        *(float4*)cp       = o0;
        *(float4*)(cp + 4) = o1;
    }
}

// ---------------- VQ pass A: per-row min of d' = e2 - 2*(ze.E^T), bf16 MFMA ----------------
__global__ __launch_bounds__(256)
void vq_minA(const unsigned short* __restrict__ zebf, const unsigned short* __restrict__ Ebf,
             const float* __restrict__ e2s, unsigned* __restrict__ gmin) {
    __shared__ unsigned short As[BM * BK];
    __shared__ unsigned short Bs[BN * BK];
    int mBase = (blockIdx.x >> 5) * BM;
    int nBase = (blockIdx.x & 31) * BN;
    int t = threadIdx.x;
    f32x4 acc[4][4];
    f32x4 zero = {0.f, 0.f, 0.f, 0.f};
#pragma unroll
    for (int i = 0; i < 4; ++i)
#pragma unroll
        for (int j = 0; j < 4; ++j) acc[i][j] = zero;

    mfma_core(zebf, Ebf, mBase, nBase, As, Bs, acc, t);

    int w = t >> 6, lane = t & 63;
    int wm = (w >> 1) * 64, wn = (w & 1) * 64;
    int g = lane >> 4, c = lane & 15;
    float e2v[4];
#pragma unroll
    for (int j = 0; j < 4; ++j) e2v[j] = e2s[nBase + wn + j * 16 + c];
#pragma unroll
    for (int i = 0; i < 4; ++i) {
#pragma unroll
        for (int rr = 0; rr < 4; ++rr) {
            float v = fmaf(-2.f, acc[i][0][rr], e2v[0]);
#pragma unroll
            for (int j = 1; j < 4; ++j)
                v = fminf(v, fmaf(-2.f, acc[i][j][rr], e2v[j]));
#pragma unroll
            for (int off = 1; off < 16; off <<= 1)
                v = fminf(v, __shfl_xor(v, off, 64));
            if (c == 0)
                atomicMin(&gmin[mBase + wm + i * 16 + g * 4 + rr], fkey(v));
        }
    }
}

// ---------------- VQ pass B: recompute d', rescore candidates in fp32, pick (d32,idx) ----------------
__global__ __launch_bounds__(256)
void vq_pickB(const unsigned short* __restrict__ zebf, const unsigned short* __restrict__ Ebf,
              const float* __restrict__ e2s, const unsigned* __restrict__ gmin,
              const float* __restrict__ ze32, const float* __restrict__ E32,
              const float* __restrict__ z2, unsigned long long* __restrict__ best) {
    __shared__ unsigned short As[BM * BK];
    __shared__ unsigned short Bs[BN * BK];
    int mBase = (blockIdx.x >> 5) * BM;
    int nBase = (blockIdx.x & 31) * BN;
    int t = threadIdx.x;
    f32x4 acc[4][4];
    f32x4 zero = {0.f, 0.f, 0.f, 0.f};
#pragma unroll
    for (int i = 0; i < 4; ++i)
#pragma unroll
        for (int j = 0; j < 4; ++j) acc[i][j] = zero;

    mfma_core(zebf, Ebf, mBase, nBase, As, Bs, acc, t);

    int w = t >> 6, lane = t & 63;
    int wm = (w >> 1) * 64, wn = (w & 1) * 64;
    int g = lane >> 4, c = lane & 15;
    float e2v[4];
#pragma unroll
    for (int j = 0; j < 4; ++j) e2v[j] = e2s[nBase + wn + j * 16 + c];
#pragma unroll
    for (int i = 0; i < 4; ++i) {
#pragma unroll
        for (int rr = 0; rr < 4; ++rr) {
            int row = mBase + wm + i * 16 + g * 4 + rr;
            float lim = funkey(gmin[row]) + MARGIN;
#pragma unroll
            for (int j = 0; j < 4; ++j) {
                float dv = fmaf(-2.f, acc[i][j][rr], e2v[j]);
                if (dv <= lim) {
                    int n = nBase + wn + j * 16 + c;
                    const float* zr = ze32 + (size_t)row * CD;
                    const float* er = E32 + (size_t)n * CD;
                    float s = 0.f;
                    for (int k = 0; k < CD; k += 4) {
                        float4 za = *(const float4*)(zr + k);
                        float4 eb = *(const float4*)(er + k);
                        s = fmaf(za.x, eb.x, s);
                        s = fmaf(za.y, eb.y, s);
                        s = fmaf(za.z, eb.z, s);
                        s = fmaf(za.w, eb.w, s);
                    }
                    float d32 = (z2[row] - 2.0f * s) + e2s[n];
                    unsigned long long key =
                        ((unsigned long long)__float_as_uint(d32) << 32) | (unsigned)n;
                    atomicMin(&best[row], key);
                }
            }
        }
    }
}

// ---------------- finish: idx, zq gather, residual, next z2 + bf16 ----------------
__global__ void vq_finish2(const float* __restrict__ ze, const float* __restrict__ E,
                           const unsigned long long* __restrict__ best,
                           float* __restrict__ nn_out, float* __restrict__ zq_out,
                           float* __restrict__ ze_next, float* __restrict__ z2_next,
                           unsigned short* __restrict__ zebf_next) {
    int w = threadIdx.x >> 6, lane = threadIdx.x & 63;
    int row = blockIdx.x * 4 + w;
    unsigned long long key = best[row];
    int idx = (int)(unsigned)(key & 0xFFFFFFFFull);
    if (lane == 0) nn_out[row] = (float)idx;
    float4 e = *(const float4*)(E + (size_t)idx * CD + lane * 4);
    float4 z = *(const float4*)(ze + (size_t)row * CD + lane * 4);
    *(float4*)(zq_out + (size_t)row * CD + lane * 4) = e;
    if (ze_next) {
        float4 r = make_float4(z.x - e.x, z.y - e.y, z.z - e.z, z.w - e.w);
        *(float4*)(ze_next + (size_t)row * CD + lane * 4) = r;
        ushort4 o = make_ushort4(f2bf(r.x), f2bf(r.y), f2bf(r.z), f2bf(r.w));
        *(ushort4*)(zebf_next + (size_t)row * CD + lane * 4) = o;
        float s = r.x * r.x + r.y * r.y + r.z * r.z + r.w * r.w;
        s = wave_sum(s);
        if (lane == 0) z2_next[row] = s;
    }
}

// ---------------- decoder input compose -> bf16 ----------------
__global__ void dcvt_kernel(const float* __restrict__ ze1, const float* __restrict__ q1,
                            const float* __restrict__ q2, const float* __restrict__ q3,
                            const float* __restrict__ q4, unsigned short* __restrict__ dibf) {
    size_t off = (size_t)(blockIdx.x * blockDim.x + threadIdx.x) * 4;
    float4 z = *(const float4*)(ze1 + off);
    float4 a = *(const float4*)(q1 + off);
    float4 b = *(const float4*)(q2 + off);
    float4 c = *(const float4*)(q3 + off);
    float4 d = *(const float4*)(q4 + off);
    float sx = ((a.x + b.x) + c.x) + d.x;
    float sy = ((a.y + b.y) + c.y) + d.y;
    float sz = ((a.z + b.z) + c.z) + d.z;
    float sw = ((a.w + b.w) + c.w) + d.w;
    ushort4 o = make_ushort4(f2bf(z.x + (sx - z.x)), f2bf(z.y + (sy - z.y)),
                             f2bf(z.z + (sz - z.z)), f2bf(z.w + (sw - z.w)));
    *(ushort4*)(dibf + off) = o;
}

// ---------------- decoder MFMA: xhat = dibf @ WdT^T + b_dec ----------------
__global__ __launch_bounds__(256)
void dec_mfma(const unsigned short* __restrict__ dibf, const unsigned short* __restrict__ WdT,
              const float* __restrict__ bias, float* __restrict__ C) {
    __shared__ unsigned short As[BM * BK];
    __shared__ unsigned short Bs[BN * BK];
    int mb = blockIdx.x / 6, nb = blockIdx.x % 6;
    int mBase = mb * BM, nBase = nb * BN;
    int t = threadIdx.x;
    f32x4 acc[4][4];
    f32x4 zero = {0.f, 0.f, 0.f, 0.f};
#pragma unroll
    for (int i = 0; i < 4; ++i)
#pragma unroll
        for (int j = 0; j < 4; ++j) acc[i][j] = zero;

    mfma_core(dibf, WdT, mBase, nBase, As, Bs, acc, t);

    int w = t >> 6, lane = t & 63;
    int wm = (w >> 1) * 64, wn = (w & 1) * 64;
    int g = lane >> 4, c = lane & 15;
    float bv[4];
#pragma unroll
    for (int j = 0; j < 4; ++j) bv[j] = bias[nBase + wn + j * 16 + c];
#pragma unroll
    for (int i = 0; i < 4; ++i)
#pragma unroll
        for (int rr = 0; rr < 4; ++rr) {
            int row = mBase + wm + i * 16 + g * 4 + rr;
#pragma unroll
            for (int j = 0; j < 4; ++j)
                C[(size_t)row * DIMIN + nBase + wn + j * 16 + c] = acc[i][j][rr] + bv[j];
        }
}

// ---------------- launch ----------------
extern "C" void kernel_launch(void* const* d_in, const int* in_sizes, int n_in,
                              void* d_out, int out_size, void* d_ws, size_t ws_size,
                              hipStream_t stream) {
    const float* x     = (const float*)d_in[0];
    const float* W_enc = (const float*)d_in[1];
    const float* b_enc = (const float*)d_in[2];
    const float* Ecb[4] = {(const float*)d_in[3], (const float*)d_in[4],
                           (const float*)d_in[5], (const float*)d_in[6]};
    const float* W_dec = (const float*)d_in[7];
    const float* b_dec = (const float*)d_in[8];

    float* out  = (float*)d_out;
    float* xhat = out;
    float* ze[4];
    float* zq[4];
    float* nn[4];
    size_t off = (size_t)NROWS * DIMIN;
    for (int i = 0; i < 4; ++i) { ze[i] = out + off; off += (size_t)NROWS * CD; }
    for (int i = 0; i < 4; ++i) { zq[i] = out + off; off += (size_t)NROWS * CD; }
    for (int i = 0; i < 4; ++i) { nn[i] = out + off; off += NROWS; }

    unsigned char* wsb = (unsigned char*)d_ws;
    unsigned long long* best = (unsigned long long*)wsb;            // 131072 B
    unsigned* gmin = (unsigned*)(wsb + 131072);                     // 65536 B
    float* z2      = (float*)(wsb + 196608);                        // 65536 B
    float* e2      = (float*)(wsb + 262144);                        // 65536 B
    unsigned short* WdT  = (unsigned short*)(wsb + 327680);         // 393216 B
    unsigned short* Ebf  = (unsigned short*)(wsb + 720896);         // 8 MB
    unsigned short* zebf = (unsigned short*)(wsb + 9109504);        // 8 MB
    unsigned short* dibf = (unsigned short*)(wsb + 17498112);       // 8 MB

    ecvt_kernel<<<4096, 256, 0, stream>>>(Ecb[0], Ecb[1], Ecb[2], Ecb[3], Ebf, e2);
    wcvt_kernel<<<768, 256, 0, stream>>>(W_dec, WdT);
    enc_gemm<<<256, 256, 0, stream>>>(x, W_enc, b_enc, ze[0], NROWS, DIMIN, CD);
    zecvt_kernel<<<4096, 256, 0, stream>>>(ze[0], zebf, z2);

    for (int s = 0; s < 4; ++s) {
        hipMemsetAsync(gmin, 0xFF, NROWS * 4, stream);
        hipMemsetAsync(best, 0xFF, NROWS * 8, stream);
        vq_minA<<<4096, 256, 0, stream>>>(zebf, Ebf + (size_t)s * KC * CD, e2 + (size_t)s * KC, gmin);
        vq_pickB<<<4096, 256, 0, stream>>>(zebf, Ebf + (size_t)s * KC * CD, e2 + (size_t)s * KC,
                                           gmin, ze[s], Ecb[s], z2, best);
        vq_finish2<<<4096, 256, 0, stream>>>(ze[s], Ecb[s], best, nn[s], zq[s],
                                             (s < 3) ? ze[s + 1] : nullptr, z2, zebf);
    }
    dcvt_kernel<<<4096, 256, 0, stream>>>(ze[0], zq[0], zq[1], zq[2], zq[3], dibf);
    dec_mfma<<<768, 256, 0, stream>>>(dibf, WdT, b_dec, xhat);
}

// Round 3
// 1080.422 us; speedup vs baseline: 3.2521x; 1.6044x over previous
//
#include <hip/hip_runtime.h>

#define NROWS 16384
#define DIMIN 768
#define CD    256
#define KC    4096

#define BM 128
#define BN 128
#define BK 32
#define MARGIN 0.10f
#define NGROUP 128   // 4096 codes / 32 per group

typedef __attribute__((ext_vector_type(8))) short short8;
typedef __attribute__((ext_vector_type(4))) float f32x4;

#define SWZ(r) ((((r) + ((r) >> 2))) & 3)
#define ASYNC_CP16(gp, lp)                                                     \
    __builtin_amdgcn_global_load_lds(                                          \
        (const __attribute__((address_space(1))) void*)(gp),                   \
        (__attribute__((address_space(3))) void*)(lp), 16, 0, 0)

// ---------------- helpers ----------------
__device__ __forceinline__ float wave_sum(float v) {
#pragma unroll
    for (int off = 32; off > 0; off >>= 1) v += __shfl_xor(v, off, 64);
    return v;
}
__device__ __forceinline__ unsigned short f2bf(float f) {
    unsigned u = __float_as_uint(f);
    unsigned r = (u + 0x7FFFu + ((u >> 16) & 1u)) >> 16;
    return (unsigned short)r;
}

// ---------------- shared MFMA core: acc[i][j] += Arows_tile . Brows_tile^T ----------------
__device__ __forceinline__ void mfma_core(const unsigned short* __restrict__ Arows,
                                          const unsigned short* __restrict__ Brows,
                                          int mBase, int nBase,
                                          unsigned short* As, unsigned short* Bs,
                                          f32x4 acc[4][4], int t) {
    int w = t >> 6, lane = t & 63;
    int wm = (w >> 1) * 64, wn = (w & 1) * 64;
    int g = lane >> 4, c = lane & 15;

    for (int kB = 0; kB < CD; kB += BK) {
        __syncthreads();
#pragma unroll
        for (int it = 0; it < 2; ++it) {
            int L = w * 128 + it * 64 + lane;  // 16B-chunk index in tile
            int r = L >> 2, p = L & 3;
            int q = p ^ SWZ(r);
            ASYNC_CP16(Arows + (size_t)(mBase + r) * CD + kB + q * 8,
                       &As[(w * 128 + it * 64) * 8]);
            ASYNC_CP16(Brows + (size_t)(nBase + r) * CD + kB + q * 8,
                       &Bs[(w * 128 + it * 64) * 8]);
        }
        __syncthreads();
        short8 a[4], b[4];
#pragma unroll
        for (int i = 0; i < 4; ++i) {
            int ra = wm + i * 16 + c;
            a[i] = *(const short8*)&As[ra * 32 + ((g ^ SWZ(ra)) << 3)];
            int rb = wn + i * 16 + c;
            b[i] = *(const short8*)&Bs[rb * 32 + ((g ^ SWZ(rb)) << 3)];
        }
#pragma unroll
        for (int i = 0; i < 4; ++i)
#pragma unroll
            for (int j = 0; j < 4; ++j)
                acc[i][j] = __builtin_amdgcn_mfma_f32_16x16x32_bf16(a[i], b[j], acc[i][j], 0, 0, 0);
    }
}

// ---------------- E -> bf16 + e2 (fp32) ----------------
__global__ void ecvt_kernel(const float* __restrict__ E1, const float* __restrict__ E2,
                            const float* __restrict__ E3, const float* __restrict__ E4,
                            unsigned short* __restrict__ Ebf, float* __restrict__ e2) {
    int gw   = (blockIdx.x * blockDim.x + threadIdx.x) >> 6;  // 0..16383
    int lane = threadIdx.x & 63;
    int cb = gw >> 12, r = gw & (KC - 1);
    const float* E = (cb == 0) ? E1 : (cb == 1) ? E2 : (cb == 2) ? E3 : E4;
    float4 v = *(const float4*)(E + (size_t)r * CD + lane * 4);
    float s  = v.x * v.x + v.y * v.y + v.z * v.z + v.w * v.w;
    s = wave_sum(s);
    if (lane == 0) e2[gw] = s;
    ushort4 o = make_ushort4(f2bf(v.x), f2bf(v.y), f2bf(v.z), f2bf(v.w));
    *(ushort4*)(Ebf + (size_t)gw * CD + lane * 4) = o;
}

// ---------------- W_dec (256x768) -> WdT (768x256 bf16, transposed) ----------------
__global__ void wcvt_kernel(const float* __restrict__ Wd, unsigned short* __restrict__ WdT) {
    int gid = blockIdx.x * blockDim.x + threadIdx.x;  // 0..196607
    int k = gid / DIMIN, n = gid % DIMIN;
    WdT[(size_t)n * CD + k] = f2bf(Wd[gid]);
}

// ---------------- ze1 -> bf16 + z2 ----------------
__global__ void zecvt_kernel(const float* __restrict__ ze, unsigned short* __restrict__ zebf,
                             float* __restrict__ z2) {
    int gw   = (blockIdx.x * blockDim.x + threadIdx.x) >> 6;
    int lane = threadIdx.x & 63;
    float4 v = *(const float4*)(ze + (size_t)gw * CD + lane * 4);
    float s  = v.x * v.x + v.y * v.y + v.z * v.z + v.w * v.w;
    s = wave_sum(s);
    if (lane == 0) z2[gw] = s;
    ushort4 o = make_ushort4(f2bf(v.x), f2bf(v.y), f2bf(v.z), f2bf(v.w));
    *(ushort4*)(zebf + (size_t)gw * CD + lane * 4) = o;
}

// ---------------- fp32 encoder GEMM, 64x64 tiles (bit-identical k-order to R1) ----------------
__global__ __launch_bounds__(256)
void enc_gemm64(const float* __restrict__ A, const float* __restrict__ B,
                const float* __restrict__ bias, float* __restrict__ C) {
    __shared__ float As[BK][64 + 4];  // As[k][m], stride 68 (16B aligned)
    __shared__ float Bs[BK][64 + 4];  // Bs[k][n]
    const int Kt = DIMIN, Nt = CD;
    int mb = blockIdx.x >> 2, nb = blockIdx.x & 3;
    int mBase = mb * 64, nBase = nb * 64;
    int t = threadIdx.x;
    int mg = t >> 4, ng = t & 15;

    float acc[4][4];
#pragma unroll
    for (int i = 0; i < 4; ++i)
#pragma unroll
        for (int j = 0; j < 4; ++j) acc[i][j] = 0.f;

    for (int kB = 0; kB < Kt; kB += BK) {
#pragma unroll
        for (int i = 0; i < 2; ++i) {  // stage A (transpose): 64 rows x 8 float4
            int idx = i * 256 + t;
            int row = idx >> 3, k4 = idx & 7;
            float4 g = *(const float4*)(A + (size_t)(mBase + row) * Kt + kB + k4 * 4);
            As[k4 * 4 + 0][row] = g.x;
            As[k4 * 4 + 1][row] = g.y;
            As[k4 * 4 + 2][row] = g.z;
            As[k4 * 4 + 3][row] = g.w;
        }
#pragma unroll
        for (int i = 0; i < 2; ++i) {  // stage B: 32 k-rows x 16 float4
            int idx = i * 256 + t;
            int row = idx >> 4, c4 = idx & 15;
            float4 g = *(const float4*)(B + (size_t)(kB + row) * Nt + nBase + c4 * 4);
            *(float4*)&Bs[row][c4 * 4] = g;
        }
        __syncthreads();
#pragma unroll 8
        for (int kk = 0; kk < BK; ++kk) {
            float4 a0 = *(const float4*)&As[kk][mg * 4];
            float4 b0 = *(const float4*)&Bs[kk][ng * 4];
            float av[4] = {a0.x, a0.y, a0.z, a0.w};
            float bv[4] = {b0.x, b0.y, b0.z, b0.w};
#pragma unroll
            for (int im = 0; im < 4; ++im)
#pragma unroll
                for (int in = 0; in < 4; ++in)
                    acc[im][in] = fmaf(av[im], bv[in], acc[im][in]);
        }
        __syncthreads();
    }
    float bv[4];
#pragma unroll
    for (int in = 0; in < 4; ++in) bv[in] = bias[nBase + ng * 4 + in];
#pragma unroll
    for (int im = 0; im < 4; ++im) {
        float4 o = make_float4(acc[im][0] + bv[0], acc[im][1] + bv[1],
                               acc[im][2] + bv[2], acc[im][3] + bv[3]);
        *(float4*)(C + (size_t)(mBase + mg * 4 + im) * Nt + nBase + ng * 4) = o;
    }
}

// ---------------- VQ pass A: d' = e2 - 2*(ze.E^T) bf16 MFMA, per-32-code-group min ----------------
__global__ __launch_bounds__(256)
void vq_minA(const unsigned short* __restrict__ zebf, const unsigned short* __restrict__ Ebf,
             const float* __restrict__ e2s, float* __restrict__ pmin) {
    __shared__ unsigned short As[BM * BK];
    __shared__ unsigned short Bs[BN * BK];
    int mBase = (blockIdx.x >> 5) * BM;
    int nBase = (blockIdx.x & 31) * BN;
    int t = threadIdx.x;
    f32x4 acc[4][4];
    f32x4 zero = {0.f, 0.f, 0.f, 0.f};
#pragma unroll
    for (int i = 0; i < 4; ++i)
#pragma unroll
        for (int j = 0; j < 4; ++j) acc[i][j] = zero;

    mfma_core(zebf, Ebf, mBase, nBase, As, Bs, acc, t);

    int w = t >> 6, lane = t & 63;
    int wm = (w >> 1) * 64, wn = (w & 1) * 64;
    int g = lane >> 4, c = lane & 15;
    float e2v[4];
#pragma unroll
    for (int j = 0; j < 4; ++j) e2v[j] = e2s[nBase + wn + j * 16 + c];
    int g0 = (nBase + wn) >> 5;  // group of codes [nBase+wn, +32)
#pragma unroll
    for (int i = 0; i < 4; ++i) {
#pragma unroll
        for (int rr = 0; rr < 4; ++rr) {
            float d0 = fmaf(-2.f, acc[i][0][rr], e2v[0]);
            float d1 = fmaf(-2.f, acc[i][1][rr], e2v[1]);
            float d2 = fmaf(-2.f, acc[i][2][rr], e2v[2]);
            float d3 = fmaf(-2.f, acc[i][3][rr], e2v[3]);
            float m01 = fminf(d0, d1), m23 = fminf(d2, d3);
#pragma unroll
            for (int off = 1; off < 16; off <<= 1) {
                m01 = fminf(m01, __shfl_xor(m01, off, 64));
                m23 = fminf(m23, __shfl_xor(m23, off, 64));
            }
            if (c == 0) {
                int row = mBase + wm + i * 16 + g * 4 + rr;
                pmin[(size_t)row * NGROUP + g0]     = m01;
                pmin[(size_t)row * NGROUP + g0 + 1] = m23;
            }
        }
    }
}

// ---------------- VQ scan: flag groups, fp32 rescore, pick, gather, residual ----------------
__global__ __launch_bounds__(256)
void vq_scan(const float* __restrict__ pmin, const float* __restrict__ ze32,
             const float* __restrict__ E32, const float* __restrict__ e2s,
             const float* __restrict__ z2,
             float* __restrict__ nn_out, float* __restrict__ zq_out,
             float* __restrict__ ze_next, float* __restrict__ z2_next,
             unsigned short* __restrict__ zebf_next) {
    int row = blockIdx.x;
    int t = threadIdx.x;
    __shared__ float zer[CD];
    __shared__ float red[4];
    __shared__ float limS;
    __shared__ int glist[NGROUP];
    __shared__ int cnt;
    __shared__ unsigned long long bestk;

    if (t == 0) { cnt = 0; bestk = ~0ull; }
    if (t < 64)
        *(float4*)&zer[t * 4] = *(const float4*)(ze32 + (size_t)row * CD + t * 4);
    float p = 3.4e38f;
    if (t < NGROUP) p = pmin[(size_t)row * NGROUP + t];
    float m = p;
#pragma unroll
    for (int off = 32; off > 0; off >>= 1) m = fminf(m, __shfl_xor(m, off, 64));
    if ((t & 63) == 0) red[t >> 6] = m;
    __syncthreads();
    if (t == 0) limS = fminf(red[0], red[1]) + MARGIN;
    __syncthreads();
    if (t < NGROUP && p <= limS) glist[atomicAdd(&cnt, 1)] = t;
    __syncthreads();

    float z2row = z2[row];
    int ncand = cnt * 32;
    unsigned long long localbest = ~0ull;
    for (int ci = t; ci < ncand; ci += 256) {
        int n = glist[ci >> 5] * 32 + (ci & 31);
        const float* er = E32 + (size_t)n * CD;
        float s = 0.f;
#pragma unroll 8
        for (int k = 0; k < CD; k += 4) {
            float4 eb = *(const float4*)(er + k);
            s = fmaf(zer[k + 0], eb.x, s);
            s = fmaf(zer[k + 1], eb.y, s);
            s = fmaf(zer[k + 2], eb.z, s);
            s = fmaf(zer[k + 3], eb.w, s);
        }
        float d32 = (z2row - 2.0f * s) + e2s[n];
        unsigned long long key =
            ((unsigned long long)__float_as_uint(d32) << 32) | (unsigned)n;
        localbest = (key < localbest) ? key : localbest;
    }
    if (localbest != ~0ull) atomicMin(&bestk, localbest);
    __syncthreads();

    int idx = (int)(unsigned)(bestk & 0xFFFFFFFFull);
    if (t == 0) nn_out[row] = (float)idx;
    if (t < 64) {
        float4 e = *(const float4*)(E32 + (size_t)idx * CD + t * 4);
        float4 z = *(const float4*)&zer[t * 4];
        *(float4*)(zq_out + (size_t)row * CD + t * 4) = e;
        if (ze_next) {
            float4 r = make_float4(z.x - e.x, z.y - e.y, z.z - e.z, z.w - e.w);
            *(float4*)(ze_next + (size_t)row * CD + t * 4) = r;
            ushort4 o = make_ushort4(f2bf(r.x), f2bf(r.y), f2bf(r.z), f2bf(r.w));
            *(ushort4*)(zebf_next + (size_t)row * CD + t * 4) = o;
            float s = r.x * r.x + r.y * r.y + r.z * r.z + r.w * r.w;
            s = wave_sum(s);
            if (t == 0) z2_next[row] = s;
        }
    }
}

// ---------------- decoder input compose -> bf16 ----------------
__global__ void dcvt_kernel(const float* __restrict__ ze1, const float* __restrict__ q1,
                            const float* __restrict__ q2, const float* __restrict__ q3,
                            const float* __restrict__ q4, unsigned short* __restrict__ dibf) {
    size_t off = (size_t)(blockIdx.x * blockDim.x + threadIdx.x) * 4;
    float4 z = *(const float4*)(ze1 + off);
    float4 a = *(const float4*)(q1 + off);
    float4 b = *(const float4*)(q2 + off);
    float4 c = *(const float4*)(q3 + off);
    float4 d = *(const float4*)(q4 + off);
    float sx = ((a.x + b.x) + c.x) + d.x;
    float sy = ((a.y + b.y) + c.y) + d.y;
    float sz = ((a.z + b.z) + c.z) + d.z;
    float sw = ((a.w + b.w) + c.w) + d.w;
    ushort4 o = make_ushort4(f2bf(z.x + (sx - z.x)), f2bf(z.y + (sy - z.y)),
                             f2bf(z.z + (sz - z.z)), f2bf(z.w + (sw - z.w)));
    *(ushort4*)(dibf + off) = o;
}

// ---------------- decoder MFMA: xhat = dibf @ WdT^T + b_dec ----------------
__global__ __launch_bounds__(256)
void dec_mfma(const unsigned short* __restrict__ dibf, const unsigned short* __restrict__ WdT,
              const float* __restrict__ bias, float* __restrict__ C) {
    __shared__ unsigned short As[BM * BK];
    __shared__ unsigned short Bs[BN * BK];
    int mb = blockIdx.x / 6, nb = blockIdx.x % 6;
    int mBase = mb * BM, nBase = nb * BN;
    int t = threadIdx.x;
    f32x4 acc[4][4];
    f32x4 zero = {0.f, 0.f, 0.f, 0.f};
#pragma unroll
    for (int i = 0; i < 4; ++i)
#pragma unroll
        for (int j = 0; j < 4; ++j) acc[i][j] = zero;

    mfma_core(dibf, WdT, mBase, nBase, As, Bs, acc, t);

    int w = t >> 6, lane = t & 63;
    int wm = (w >> 1) * 64, wn = (w & 1) * 64;
    int g = lane >> 4, c = lane & 15;
    float bv[4];
#pragma unroll
    for (int j = 0; j < 4; ++j) bv[j] = bias[nBase + wn + j * 16 + c];
#pragma unroll
    for (int i = 0; i < 4; ++i)
#pragma unroll
        for (int rr = 0; rr < 4; ++rr) {
            int row = mBase + wm + i * 16 + g * 4 + rr;
#pragma unroll
            for (int j = 0; j < 4; ++j)
                C[(size_t)row * DIMIN + nBase + wn + j * 16 + c] = acc[i][j][rr] + bv[j];
        }
}

// ---------------- launch ----------------
extern "C" void kernel_launch(void* const* d_in, const int* in_sizes, int n_in,
                              void* d_out, int out_size, void* d_ws, size_t ws_size,
                              hipStream_t stream) {
    const float* x     = (const float*)d_in[0];
    const float* W_enc = (const float*)d_in[1];
    const float* b_enc = (const float*)d_in[2];
    const float* Ecb[4] = {(const float*)d_in[3], (const float*)d_in[4],
                           (const float*)d_in[5], (const float*)d_in[6]};
    const float* W_dec = (const float*)d_in[7];
    const float* b_dec = (const float*)d_in[8];

    float* out  = (float*)d_out;
    float* xhat = out;
    float* ze[4];
    float* zq[4];
    float* nn[4];
    size_t off = (size_t)NROWS * DIMIN;
    for (int i = 0; i < 4; ++i) { ze[i] = out + off; off += (size_t)NROWS * CD; }
    for (int i = 0; i < 4; ++i) { zq[i] = out + off; off += (size_t)NROWS * CD; }
    for (int i = 0; i < 4; ++i) { nn[i] = out + off; off += NROWS; }

    unsigned char* wsb = (unsigned char*)d_ws;
    float* z2            = (float*)wsb;                              // 64 KB
    float* e2            = (float*)(wsb + 65536);                    // 64 KB
    unsigned short* WdT  = (unsigned short*)(wsb + 131072);          // 384 KB
    float* pmin          = (float*)(wsb + 524288);                   // 8 MB
    unsigned short* dibf = (unsigned short*)(wsb + 524288);          // aliases pmin (dead after VQ loop)
    unsigned short* Ebf  = (unsigned short*)(wsb + 8912896);         // 8 MB
    unsigned short* zebf = (unsigned short*)(wsb + 17301504);        // 8 MB

    ecvt_kernel<<<4096, 256, 0, stream>>>(Ecb[0], Ecb[1], Ecb[2], Ecb[3], Ebf, e2);
    wcvt_kernel<<<768, 256, 0, stream>>>(W_dec, WdT);
    enc_gemm64<<<1024, 256, 0, stream>>>(x, W_enc, b_enc, ze[0]);
    zecvt_kernel<<<4096, 256, 0, stream>>>(ze[0], zebf, z2);

    for (int s = 0; s < 4; ++s) {
        vq_minA<<<4096, 256, 0, stream>>>(zebf, Ebf + (size_t)s * KC * CD,
                                          e2 + (size_t)s * KC, pmin);
        vq_scan<<<NROWS, 256, 0, stream>>>(pmin, ze[s], Ecb[s], e2 + (size_t)s * KC, z2,
                                           nn[s], zq[s],
                                           (s < 3) ? ze[s + 1] : nullptr, z2, zebf);
    }
    dcvt_kernel<<<4096, 256, 0, stream>>>(ze[0], zq[0], zq[1], zq[2], zq[3], dibf);
    dec_mfma<<<768, 256, 0, stream>>>(dibf, WdT, b_dec, xhat);
}